// Round 4
// baseline (2438.322 us; speedup 1.0000x reference)
//
#include <hip/hip_runtime.h>

// FeedBack LSTM: B=1024, T_in=128, F=3, UNITS=256, out_steps=32.
// R4: column-partitioned systolic design.
//   grid = 256 blocks x 512 threads (8 waves) -> one block per CU.
//   group g (64 groups) owns batch rows g*16..g*16+15; its 4 members
//   (same XCD under bid%8 round-robin: bids x+32*s+8*m) each hold a fixed
//   256-column slice of Wr IN REGISTERS (16 B-frags/wave = 64 VGPR).
//   Per step: 16 MFMA/wave -> gates (wave-local via gate-interleaved column
//   packing + shfl_xor(8)) -> publish 2KB h-chunk to L2 exchange buffer
//   (release fence + flag) -> spin for 3 peers -> acquire fence -> reload
//   full h (8KB, stored in A-fragment order, coalesced dwordx4).
// Weights are NEVER re-read after the prologue.

#define TIN    128
#define OSTEPS 32
#define TOTAL  (TIN + OSTEPS - 1)   // 159 h-producing steps (t = 0..158)

typedef float    f32x4 __attribute__((ext_vector_type(4)));
typedef _Float16 half8 __attribute__((ext_vector_type(8)));

__device__ __forceinline__ float fast_rcp(float x) { return __builtin_amdgcn_rcpf(x); }
__device__ __forceinline__ float sigm(float x)  { return fast_rcp(1.0f + __expf(-x)); }
__device__ __forceinline__ float tanh_f(float x){ return 1.0f - 2.0f * fast_rcp(__expf(2.0f * x) + 1.0f); }

// Pack Wr [256][1024] fp32 -> fp16 B-frags, tile T = m*16 + w*2 + ct:
// tile-col n (0..15) -> global col (ct*2 + (n>>3))*256 + m*64 + w*8 + (n&7)
// P[(T*8 + kt)*512 + l*8 + j] = Wr[kt*32 + (l>>4)*8 + j][col(l&15)]
__global__ __launch_bounds__(512) void pack_wr(const float* __restrict__ Wr,
                                               _Float16* __restrict__ P)
{
    int idx = blockIdx.x * 512 + threadIdx.x;   // 64 blocks -> idx < 32768
    int l   = idx & 63;
    int kt  = (idx >> 6) & 7;
    int T   = idx >> 9;                         // 0..63
    int m = T >> 4, w = (T >> 1) & 7, ct = T & 1;
    int gate = ct * 2 + ((l >> 3) & 1);
    int col  = gate * 256 + m * 64 + w * 8 + (l & 7);
    int k0   = kt * 32 + (l >> 4) * 8;
    half8 v;
#pragma unroll
    for (int j = 0; j < 8; ++j) v[j] = (_Float16)Wr[(k0 + j) * 1024 + col];
    *reinterpret_cast<half8*>(P + (size_t)idx * 8) = v;
}

__global__ __launch_bounds__(512, 2) void lstm_sys(
    const float* __restrict__ x_in,   // [1024][128][3]
    const float* __restrict__ Wk,     // [3][1024]
    const float* __restrict__ bias,   // [1024]
    const float* __restrict__ Wd,     // [256][3]
    const float* __restrict__ bd,     // [3]
    const _Float16* __restrict__ WrP, // packed B-frags
    _Float16* __restrict__ hex,       // [2 buf][64 grp][4096] halves (A-frag order)
    unsigned*  __restrict__ flags,    // [64 grp][32] (128B-strided counters)
    float* __restrict__ out)          // [1024][32][3]
{
    __shared__ float xs[16 * TIN * 3];        // 24 KB staged inputs
    __shared__ float pred_buf[16][4];         // fed-back prediction

    const int tid  = threadIdx.x;
    const int w    = tid >> 6;                // wave 0..7
    const int l    = tid & 63;
    const int row0 = (l >> 4) * 4;            // MFMA C rows for this lane
    const int bid  = blockIdx.x;
    const int m    = (bid >> 3) & 3;                  // member 0..3
    const int g    = (bid & 7) + 8 * (bid >> 5);      // group 0..63 (same-XCD members)

    // ---- prologue ----
    const float* xsrc = x_in + (size_t)g * 16 * TIN * 3;
    for (int i = tid; i < 16 * TIN * 3; i += 512) xs[i] = xsrc[i];

    half8 bfr[2][8];                          // register-resident weight slice
    const int T0 = m * 16 + w * 2;
#pragma unroll
    for (int ct = 0; ct < 2; ++ct)
#pragma unroll
        for (int kt = 0; kt < 8; ++kt)
            bfr[ct][kt] = *reinterpret_cast<const half8*>(
                WrP + ((size_t)(T0 + ct) * 8 + kt) * 512 + l * 8);

    float wk_r[2][3], b_r[2];
#pragma unroll
    for (int ct = 0; ct < 2; ++ct) {
        int gate = ct * 2 + ((l >> 3) & 1);
        int col  = gate * 256 + m * 64 + w * 8 + (l & 7);
        b_r[ct] = bias[col];
#pragma unroll
        for (int f = 0; f < 3; ++f) wk_r[ct][f] = Wk[f * 1024 + col];
    }
    float wd_r[4][3];                          // pred head: lane handles units l+64q
#pragma unroll
    for (int q = 0; q < 4; ++q)
#pragma unroll
        for (int f = 0; f < 3; ++f) wd_r[q][f] = Wd[(l + 64 * q) * 3 + f];
    const float bd0 = bd[0], bd1 = bd[1], bd2 = bd[2];

    float c_st[4] = {0.f, 0.f, 0.f, 0.f};      // lanes with (l&8)==0 own a unit
    const int u_g        = m * 64 + w * 8 + (l & 7);
    const int hstore_off = (u_g >> 5) * 512 + ((u_g >> 3) & 3) * 128 + (u_g & 7);
    unsigned* cnt = flags + g * 32;

    __syncthreads();

    for (int t = 0; t <= TOTAL; ++t) {         // t==TOTAL(159): pred-only epilogue
        const int rd = (t & 1) ^ 1;            // buffer holding h_{t-1}

        // ---- group sync: wait until all 4 members published h_{t-1} ----
        if (t > 0) {
            if (tid == 0) {
                const unsigned tgt = 4u * (unsigned)t;
                while (__hip_atomic_load(cnt, __ATOMIC_RELAXED,
                                         __HIP_MEMORY_SCOPE_AGENT) < tgt) { }
                __threadfence();               // acquire: invalidate L1/L2
            }
            __syncthreads();
        }
        const _Float16* hrd = hex + (size_t)(rd * 64 + g) * 4096;

        // ---- pred phase (t>=128): pred from h_{t-1}; output s = t-128 ----
        if (t >= TIN) {
            const int s = t - TIN;
#pragma unroll
            for (int rr = 0; rr < 2; ++rr) {
                int row = 2 * w + rr;          // wave w reduces rows 2w, 2w+1
                float p0 = 0.f, p1 = 0.f, p2 = 0.f;
#pragma unroll
                for (int q = 0; q < 4; ++q) {
                    int u   = l + 64 * q;
                    int off = (u >> 5) * 512 + ((u >> 3) & 3) * 128 + row * 8 + (u & 7);
                    float hv = (float)hrd[off];
                    p0 += hv * wd_r[q][0];
                    p1 += hv * wd_r[q][1];
                    p2 += hv * wd_r[q][2];
                }
#pragma unroll
                for (int o = 32; o > 0; o >>= 1) {
                    p0 += __shfl_xor(p0, o);
                    p1 += __shfl_xor(p1, o);
                    p2 += __shfl_xor(p2, o);
                }
                if (l == 0) {
                    p0 += bd0; p1 += bd1; p2 += bd2;
                    pred_buf[row][0] = p0; pred_buf[row][1] = p1; pred_buf[row][2] = p2;
                    if (m == 0) {
                        float* op = out + ((size_t)(g * 16 + row) * OSTEPS + s) * 3;
                        op[0] = p0; op[1] = p1; op[2] = p2;
                    }
                }
            }
            __syncthreads();
            if (t == TOTAL) break;             // s=31 stored; done
        }

        // ---- A-fragments: full h_{t-1} (coalesced; zeros at t=0) ----
        half8 a[8];
        if (t > 0) {
#pragma unroll
            for (int kt = 0; kt < 8; ++kt)
                a[kt] = *reinterpret_cast<const half8*>(hrd + kt * 512 + l * 8);
        } else {
            half8 az = {};
#pragma unroll
            for (int kt = 0; kt < 8; ++kt) a[kt] = az;
        }

        // ---- x for this step ----
        float xv[4][3];
#pragma unroll
        for (int r = 0; r < 4; ++r) {
            int row = row0 + r;
            if (t >= TIN) {
                xv[r][0] = pred_buf[row][0];
                xv[r][1] = pred_buf[row][1];
                xv[r][2] = pred_buf[row][2];
            } else {
                const float* xp = &xs[(row * TIN + t) * 3];
                xv[r][0] = xp[0]; xv[r][1] = xp[1]; xv[r][2] = xp[2];
            }
        }

        // ---- z = b + x@Wk + h@Wr (16 MFMA, weights in registers) ----
        f32x4 acc[2];
#pragma unroll
        for (int ct = 0; ct < 2; ++ct)
#pragma unroll
            for (int r = 0; r < 4; ++r)
                acc[ct][r] = b_r[ct] + xv[r][0] * wk_r[ct][0]
                           + xv[r][1] * wk_r[ct][1] + xv[r][2] * wk_r[ct][2];
#pragma unroll
        for (int kt = 0; kt < 8; ++kt)
#pragma unroll
            for (int ct = 0; ct < 2; ++ct)
                acc[ct] = __builtin_amdgcn_mfma_f32_16x16x32_f16(a[kt], bfr[ct][kt], acc[ct], 0, 0, 0);

        // ---- gates: unit's {i,f} in acc[0] lanes n / n+8, {g,o} in acc[1] ----
        float shA[4], shB[4];
#pragma unroll
        for (int r = 0; r < 4; ++r) {
            shA[r] = __shfl_xor(acc[0][r], 8);
            shB[r] = __shfl_xor(acc[1][r], 8);
        }
        _Float16* hwr = hex + (size_t)((t & 1) * 64 + g) * 4096;
        if ((l & 8) == 0) {                    // lanes n<8 own unit u_g
#pragma unroll
            for (int r = 0; r < 4; ++r) {
                float iv = sigm(acc[0][r]);
                float fv = sigm(shA[r]);
                float gv = tanh_f(acc[1][r]);
                float ov = sigm(shB[r]);
                float cc = fv * c_st[r] + iv * gv;
                c_st[r] = cc;
                float hv = ov * tanh_f(cc);
                hwr[hstore_off + (row0 + r) * 8] = (_Float16)hv;
            }
        }

        // ---- publish: drain stores, release fence, bump group counter ----
        __syncthreads();                       // compiler emits vmcnt(0) before barrier
        if (tid == 0) {
            __threadfence();                   // release: write back to coherence point
            __hip_atomic_fetch_add(cnt, 1u, __ATOMIC_RELAXED, __HIP_MEMORY_SCOPE_AGENT);
        }
    }
}

extern "C" void kernel_launch(void* const* d_in, const int* in_sizes, int n_in,
                              void* d_out, int out_size, void* d_ws, size_t ws_size,
                              hipStream_t stream)
{
    const float* x  = (const float*)d_in[0];
    const float* Wk = (const float*)d_in[1];
    const float* Wr = (const float*)d_in[2];
    const float* b  = (const float*)d_in[3];
    const float* Wd = (const float*)d_in[4];
    const float* bd = (const float*)d_in[5];
    float* out = (float*)d_out;

    // d_ws layout: [0,8K) flags | [8K, 8K+512K) WrP | [8K+512K, +1M) h exchange
    unsigned*  flags = (unsigned*)d_ws;
    _Float16*  WrP   = (_Float16*)((char*)d_ws + 8192);
    _Float16*  hex   = (_Float16*)((char*)d_ws + 8192 + 524288);

    hipMemsetAsync(d_ws, 0, 8192, stream);               // zero group counters
    pack_wr<<<64, 512, 0, stream>>>(Wr, WrP);
    lstm_sys<<<256, 512, 0, stream>>>(x, Wk, b, Wd, bd, WrP, hex, flags, out);
}

// Round 6
// 427.434 us; speedup vs baseline: 5.7046x; 5.7046x over previous
//
#include <hip/hip_runtime.h>

// FeedBack LSTM: B=1024, T_in=128, F=3, UNITS=256, out_steps=32.
// R6: 2-member groups, register-resident weights, atomic-exchange (NO inline asm).
//   128 blocks x 512 threads (8 waves). Group g owns batch rows g*16..+15;
//   member p holds Wr columns for units [p*128,(p+1)*128) x 4 gates in
//   REGISTERS: 4 col-tiles/wave x 8 kt = 32 half8 = 128 VGPR (launch_bounds
//   (512,2) -> 256-VGPR cap). Members paired same-XCD (bid, bid^8).
//   Exchange: h halves as relaxed AGENT-scope u64 atomics (compiler-lowered,
//   vmcnt-tracked -> the s_waitcnt vmcnt(0) before s_barrier orders stores
//   before the counter bump; R4 proved the spin+counter protocol, R6 removes
//   its __threadfence/wbl2 cost). Peer half broadcast via LDS hfull, which
//   holds ALL 8 k-tiles in global A-frag order -> static indexing everywhere.

#define TIN    128
#define FIN    3
#define OSTEPS 32
#define LASTT  (TIN + OSTEPS - 1)   // t = 0..159; t==159 is head-only

typedef float    f32x4 __attribute__((ext_vector_type(4)));
typedef _Float16 half8 __attribute__((ext_vector_type(8)));
typedef unsigned long long u64;

__device__ __forceinline__ float fast_rcp(float x) { return __builtin_amdgcn_rcpf(x); }
__device__ __forceinline__ float sigm(float x)  { return fast_rcp(1.0f + __expf(-x)); }
__device__ __forceinline__ float tanh_f(float x){ return 1.0f - 2.0f * fast_rcp(__expf(2.0f * x) + 1.0f); }

// Pack Wr [256][1024] fp32 -> fp16 B-frags. Tile T = p*32 + q*8 + w covers
// cols q*256 + p*128 + w*16 + (l&15); k = kt*32 + (l>>4)*8 + j.
// P[(T*8+kt)*512 + l*8 + j] = Wr[k][col]
__global__ __launch_bounds__(512) void pack_wr(const float* __restrict__ Wr,
                                               _Float16* __restrict__ P)
{
    int idx = blockIdx.x * 512 + threadIdx.x;   // 64 blocks -> 32768
    int l   = idx & 63;
    int kt  = (idx >> 6) & 7;
    int T   = idx >> 9;                         // 0..63
    int p = T >> 5, q = (T >> 3) & 3, w = T & 7;
    int col = q * 256 + p * 128 + w * 16 + (l & 15);
    int k0  = kt * 32 + (l >> 4) * 8;
    half8 v;
#pragma unroll
    for (int j = 0; j < 8; ++j) v[j] = (_Float16)Wr[(k0 + j) * 1024 + col];
    *reinterpret_cast<half8*>(P + (size_t)idx * 8) = v;
}

__global__ __launch_bounds__(512, 2) void lstm_pair(
    const float* __restrict__ x_in,   // [1024][128][3]
    const float* __restrict__ Wk,     // [3][1024]
    const float* __restrict__ bias,   // [1024]
    const float* __restrict__ Wd,     // [256][3]
    const float* __restrict__ bd,     // [3]
    const _Float16* __restrict__ WrP, // packed B-frags
    u64*       __restrict__ hex,      // [2 par][64 grp][1024] u64 (A-frag order)
    unsigned*  __restrict__ flags,    // [64 grp][2 mem] counters, 64B apart
    float* __restrict__ out)          // [1024][32][3]
{
    __shared__ float                xs[16 * TIN * FIN];  // 24 KB staged inputs
    __shared__ alignas(16) _Float16 hfull[2][4096];      // full h, A-frag order, 16 KB
    __shared__ float                pred_buf[16][4];     // fed-back prediction

    const int tid  = threadIdx.x;
    const int w    = tid >> 6;            // wave 0..7
    const int l    = tid & 63;
    const int n    = l & 15;
    const int row0 = (l >> 4) * 4;        // MFMA C rows for this lane
    const int bid  = blockIdx.x;
    const int p    = (bid >> 3) & 1;      // member: units [p*128,(p+1)*128)
    const int pp   = 1 - p;
    const int g    = (bid & 7) + 8 * (bid >> 4);   // group 0..63; pair = same XCD

    // ---- prologue ----
    const float* xsrc = x_in + (size_t)g * 16 * TIN * FIN;
    for (int i = tid; i < 16 * TIN * FIN; i += 512) xs[i] = xsrc[i];

    half8 bfr[4][8];                      // register-resident weight slice (128 VGPR)
#pragma unroll
    for (int q = 0; q < 4; ++q)
#pragma unroll
        for (int kt = 0; kt < 8; ++kt)
            bfr[q][kt] = *reinterpret_cast<const half8*>(
                WrP + (((size_t)(p * 32 + q * 8 + w) * 8 + kt) * 512 + l * 8));

    float b_r[4], wk_r[4][3];
#pragma unroll
    for (int q = 0; q < 4; ++q) {
        int col = q * 256 + p * 128 + w * 16 + n;
        b_r[q] = bias[col];
#pragma unroll
        for (int f = 0; f < 3; ++f) wk_r[q][f] = Wk[f * 1024 + col];
    }
    float wd_r[4][3];                     // head: lane l covers units 4l..4l+3
#pragma unroll
    for (int j = 0; j < 4; ++j)
#pragma unroll
        for (int f = 0; f < 3; ++f) wd_r[j][f] = Wd[(4 * l + j) * 3 + f];
    const float bd0 = bd[0], bd1 = bd[1], bd2 = bd[2];

    float c_st[4] = {0.f, 0.f, 0.f, 0.f};
    // own h store position (global A-frag index, within member-p region):
    const int hpos = p * 2048 + (w >> 1) * 512 + ((2 * w + (n >> 3)) & 3) * 128
                   + row0 * 8 + (n & 7);

    unsigned* cnt_my   = flags + ((size_t)g * 2 + p)  * 16;
    unsigned* cnt_peer = flags + ((size_t)g * 2 + pp) * 16;

    __syncthreads();

    for (int t = 0; t <= LASTT; ++t) {
        const int par_rd = (t - 1) & 1;   // parity holding h_{t-1} (t>0)

        // ---- acquire h_{t-1}: spin, then pull peer half into LDS ----
        if (t > 0) {
            if (tid == 0) {
                while (__hip_atomic_load(cnt_peer, __ATOMIC_RELAXED,
                                         __HIP_MEMORY_SCOPE_AGENT) < (unsigned)t) { }
            }
            __syncthreads();
            const u64* hexr = hex + ((size_t)(par_rd * 64 + g)) * 1024 + pp * 512;
            u64 v = __hip_atomic_load(hexr + tid, __ATOMIC_RELAXED,
                                      __HIP_MEMORY_SCOPE_AGENT);
            reinterpret_cast<u64*>(&hfull[par_rd][pp * 2048])[tid] = v;
            __syncthreads();
        }

        // ---- head phase (t>=128): pred_s from h_{t-1}, s = t-128 ----
        if (t >= TIN) {
            const int s = t - TIN;
#pragma unroll
            for (int rr = 0; rr < 2; ++rr) {
                int row = 2 * w + rr;     // wave w reduces batch rows 2w, 2w+1
                const _Float16* hb = &hfull[par_rd][(l >> 3) * 512
                                   + ((l >> 1) & 3) * 128 + row * 8 + 4 * (l & 1)];
                float p0 = 0.f, p1 = 0.f, p2 = 0.f;
#pragma unroll
                for (int j = 0; j < 4; ++j) {
                    float hj = (float)hb[j];
                    p0 += hj * wd_r[j][0];
                    p1 += hj * wd_r[j][1];
                    p2 += hj * wd_r[j][2];
                }
#pragma unroll
                for (int o = 32; o > 0; o >>= 1) {
                    p0 += __shfl_xor(p0, o);
                    p1 += __shfl_xor(p1, o);
                    p2 += __shfl_xor(p2, o);
                }
                if (l == 0) {
                    p0 += bd0; p1 += bd1; p2 += bd2;
                    pred_buf[row][0] = p0; pred_buf[row][1] = p1; pred_buf[row][2] = p2;
                    if (p == 0) {
                        float* op = out + ((size_t)(g * 16 + row) * OSTEPS + s) * 3;
                        op[0] = p0; op[1] = p1; op[2] = p2;
                    }
                }
            }
            __syncthreads();              // pred_buf ready for the cell below
            if (t == LASTT) break;        // s=31 stored; done
        }

        // ---- A-fragments (static indices; zeros at t=0) ----
        half8 a[8];
        if (t > 0) {
#pragma unroll
            for (int kt = 0; kt < 8; ++kt)
                a[kt] = *reinterpret_cast<const half8*>(&hfull[par_rd][kt * 512 + l * 8]);
        } else {
            half8 az = {};
#pragma unroll
            for (int kt = 0; kt < 8; ++kt) a[kt] = az;
        }

        // ---- x for this cell step ----
        float xv[4][3];
#pragma unroll
        for (int r = 0; r < 4; ++r) {
            int row = row0 + r;
            if (t >= TIN) {
                xv[r][0] = pred_buf[row][0];
                xv[r][1] = pred_buf[row][1];
                xv[r][2] = pred_buf[row][2];
            } else {
                const float* xp = &xs[(row * TIN + t) * 3];
                xv[r][0] = xp[0]; xv[r][1] = xp[1]; xv[r][2] = xp[2];
            }
        }

        // ---- z = b + x@Wk + h@Wr (32 MFMA, weights in registers) ----
        f32x4 acc[4];
#pragma unroll
        for (int q = 0; q < 4; ++q)
#pragma unroll
            for (int r = 0; r < 4; ++r)
                acc[q][r] = b_r[q] + xv[r][0] * wk_r[q][0]
                          + xv[r][1] * wk_r[q][1] + xv[r][2] * wk_r[q][2];
#pragma unroll
        for (int kt = 0; kt < 8; ++kt)
#pragma unroll
            for (int q = 0; q < 4; ++q)
                acc[q] = __builtin_amdgcn_mfma_f32_16x16x32_f16(a[kt], bfr[q][kt], acc[q], 0, 0, 0);

        // ---- gates (all in-lane), c update, own-half h write to LDS ----
        const int par_wr = t & 1;
#pragma unroll
        for (int r = 0; r < 4; ++r) {
            float iv = sigm(acc[0][r]);
            float fv = sigm(acc[1][r]);
            float gv = tanh_f(acc[2][r]);
            float ov = sigm(acc[3][r]);
            float cc = fv * c_st[r] + iv * gv;
            c_st[r] = cc;
            hfull[par_wr][hpos + r * 8] = (_Float16)(ov * tanh_f(cc));
        }
        __syncthreads();                  // own region of hfull[par_wr] complete

        // ---- publish own half (atomic u64, agent scope, vmcnt-tracked) ----
        {
            u64 v = reinterpret_cast<const u64*>(&hfull[par_wr][p * 2048])[tid];
            u64* hexw = hex + ((size_t)(par_wr * 64 + g)) * 1024 + p * 512;
            __hip_atomic_store(hexw + tid, v, __ATOMIC_RELAXED,
                               __HIP_MEMORY_SCOPE_AGENT);
        }
        __syncthreads();   // compiler drains vmcnt(0) per wave before s_barrier
        if (tid == 0)
            __hip_atomic_store(cnt_my, (unsigned)(t + 1), __ATOMIC_RELAXED,
                               __HIP_MEMORY_SCOPE_AGENT);
    }
}

extern "C" void kernel_launch(void* const* d_in, const int* in_sizes, int n_in,
                              void* d_out, int out_size, void* d_ws, size_t ws_size,
                              hipStream_t stream)
{
    const float* x  = (const float*)d_in[0];
    const float* Wk = (const float*)d_in[1];
    const float* Wr = (const float*)d_in[2];
    const float* b  = (const float*)d_in[3];
    const float* Wd = (const float*)d_in[4];
    const float* bd = (const float*)d_in[5];
    float* out = (float*)d_out;

    // d_ws: [0,8K) flags | [8K, 8K+512K) WrP | [8K+512K, +1M) hex  (= R4 footprint)
    unsigned* flags = (unsigned*)d_ws;
    _Float16* WrP   = (_Float16*)((char*)d_ws + 8192);
    u64*      hex   = (u64*)((char*)d_ws + 8192 + 524288);

    hipMemsetAsync(d_ws, 0, 8192, stream);          // zero group counters
    pack_wr<<<64, 512, 0, stream>>>(Wr, WrP);
    lstm_pair<<<128, 512, 0, stream>>>(x, Wk, b, Wd, bd, WrP, hex, flags, out);
}